// Round 1
// baseline (108.603 us; speedup 1.0000x reference)
//
#include <hip/hip_runtime.h>

// 1-NN (squared-L2 argmin over 500000x256 f32 keys) + dot(values[idx], query).
// Memory-bound: 512 MB of keys must stream once -> ~81 us floor at 6.3 TB/s.

#define D 256
#define D4 (D / 4)            // 64 float4 per row == one wave, 1 float4/lane
#define BLOCK 256
#define GRID 2048             // 8192 waves; ~62 contiguous rows per wave

// Map float -> monotonically ordered uint (no NaNs in this problem).
__device__ __forceinline__ unsigned int fkey(float f) {
    unsigned int u = __float_as_uint(f);
    return (u & 0x80000000u) ? ~u : (u | 0x80000000u);
}

__global__ __launch_bounds__(BLOCK) void nn_argmin_kernel(
    const float* __restrict__ query,
    const float* __restrict__ keys,
    unsigned long long* __restrict__ best,   // packed (fkey(dist)<<32)|row
    int N)
{
    const int lane  = threadIdx.x & 63;
    const int wib   = threadIdx.x >> 6;               // wave in block
    const int wpb   = BLOCK >> 6;                     // waves per block
    const int gwave = blockIdx.x * wpb + wib;
    const int nwav  = GRID * wpb;

    // Per-lane query fragment (constant across rows).
    const float4 q = reinterpret_cast<const float4*>(query)[lane];
    const float4 qm2 = make_float4(-2.f * q.x, -2.f * q.y, -2.f * q.z, -2.f * q.w);

    // Contiguous chunk of rows per wave (streams ~62 KB contiguously).
    const int chunk = (N + nwav - 1) / nwav;
    const int r0 = gwave * chunk;
    const int r1 = min(N, r0 + chunk);

    unsigned long long myBest = 0xFFFFFFFFFFFFFFFFull;

    const float4* __restrict__ k4 = reinterpret_cast<const float4*>(keys);

    int r = r0;
    // 2 rows per iteration: two independent loads in flight per wave.
    for (; r + 1 < r1; r += 2) {
        float4 a = k4[(size_t)r       * D4 + lane];
        float4 b = k4[(size_t)(r + 1) * D4 + lane];
        float pa = a.x * (a.x + qm2.x) + a.y * (a.y + qm2.y)
                 + a.z * (a.z + qm2.z) + a.w * (a.w + qm2.w);
        float pb = b.x * (b.x + qm2.x) + b.y * (b.y + qm2.y)
                 + b.z * (b.z + qm2.z) + b.w * (b.w + qm2.w);
        #pragma unroll
        for (int off = 32; off; off >>= 1) {
            pa += __shfl_down(pa, off, 64);
            pb += __shfl_down(pb, off, 64);
        }
        if (lane == 0) {
            unsigned long long ka = ((unsigned long long)fkey(pa) << 32) | (unsigned int)r;
            unsigned long long kb = ((unsigned long long)fkey(pb) << 32) | (unsigned int)(r + 1);
            if (ka < myBest) myBest = ka;
            if (kb < myBest) myBest = kb;
        }
    }
    if (r < r1) {
        float4 a = k4[(size_t)r * D4 + lane];
        float pa = a.x * (a.x + qm2.x) + a.y * (a.y + qm2.y)
                 + a.z * (a.z + qm2.z) + a.w * (a.w + qm2.w);
        #pragma unroll
        for (int off = 32; off; off >>= 1) pa += __shfl_down(pa, off, 64);
        if (lane == 0) {
            unsigned long long ka = ((unsigned long long)fkey(pa) << 32) | (unsigned int)r;
            if (ka < myBest) myBest = ka;
        }
    }

    // Block reduction: one atomic per block (order-independent packed min).
    __shared__ unsigned long long s_best[wpb];
    if (lane == 0) s_best[wib] = myBest;
    __syncthreads();
    if (threadIdx.x == 0) {
        unsigned long long m = s_best[0];
        #pragma unroll
        for (int i = 1; i < wpb; ++i) m = min(m, s_best[i]);
        if (m != 0xFFFFFFFFFFFFFFFFull) atomicMin(best, m);
    }
}

__global__ __launch_bounds__(64) void nn_dot_kernel(
    const float* __restrict__ query,
    const float* __restrict__ values,
    const unsigned long long* __restrict__ best,
    float* __restrict__ out)
{
    const int lane = threadIdx.x;
    const int idx = (int)(*best & 0xFFFFFFFFull);
    const float4 v = reinterpret_cast<const float4*>(values + (size_t)idx * D)[lane];
    const float4 q = reinterpret_cast<const float4*>(query)[lane];
    float d = v.x * q.x + v.y * q.y + v.z * q.z + v.w * q.w;
    #pragma unroll
    for (int off = 32; off; off >>= 1) d += __shfl_down(d, off, 64);
    if (lane == 0) out[0] = d;
}

extern "C" void kernel_launch(void* const* d_in, const int* in_sizes, int n_in,
                              void* d_out, int out_size, void* d_ws, size_t ws_size,
                              hipStream_t stream) {
    const float* query  = (const float*)d_in[0];
    const float* keys   = (const float*)d_in[1];
    const float* values = (const float*)d_in[2];
    const int N = in_sizes[1] / D;

    unsigned long long* best = (unsigned long long*)d_ws;
    // ws is NOT re-poisoned between replays -> init every call (capture-safe).
    hipMemsetAsync(d_ws, 0xFF, sizeof(unsigned long long), stream);

    nn_argmin_kernel<<<GRID, BLOCK, 0, stream>>>(query, keys, best, N);
    nn_dot_kernel<<<1, 64, 0, stream>>>(query, values, best, (float*)d_out);
}